// Round 1
// 730.827 us; speedup vs baseline: 1.5078x; 1.5078x over previous
//
#include <hip/hip_runtime.h>
#include <math.h>

// GatingFunc: logits = x @ W^T + b; top-2 -> softmax -> scatter to [N, E].
// N=131072, D=1024, E=64, K=2 (fp32 in/out).
//
// Round 4: MFMA rewrite. Old structure was DS-pipe bound (256 broadcast
// ds_read_b128/CU/q-step vs 1024 cy FMA issue -> VALUBusy 34%, 615 us).
// New: split-bf16 GEMM on matrix cores (x=xh+xl, W=wh+wl, 3 MFMA passes
// ~= fp32 precision; logit err ~1e-5), HBM-bound target ~90-130 us.
//  - wave = 64 tokens x 64 experts, mfma_f32_16x16x32_bf16.
//    C/D: col=lane&15 (token), row=(lane>>4)*4+reg (expert)  [HW-verified].
//  - W pre-packed by prep kernel into per-lane fragment order, bf16 hi/lo,
//    in d_ws (256 KB, L2-resident) -> coalesced dwordx4 frag loads.
//  - x loaded directly in fragment layout (row 128B-chunk fully consumed by
//    an instr pair -> no overfetch), converted hi/lo in-register,
//    double-buffered one K-step ahead. W single-buffered (L2-hot, and its
//    vmcnt wait leaves the 8 younger x loads in flight).
//  - epilogue: per-token local top-2 scan (16 vals) + 2 shfl_xor merges;
//    4 KB LDS scratch redistributes (i1,i2,g1,g2) for coalesced f32x4 writes.

#define D_MODEL 1024
#define N_EXP   64
#define NSTEP   32          // K-steps of 32 (MFMA K)
#define BLOCK   256
#define TOK_PER_WAVE  64
#define TOK_PER_BLOCK 256

typedef float  f32x4 __attribute__((ext_vector_type(4)));
typedef __bf16 bf16x8 __attribute__((ext_vector_type(8)));

// ---- prep: pack W [64][1024] fp32 -> bf16 hi/lo A-fragments ----
// chunk c = (s*4 + g)*64 + l holds W[e = g*16 + (l&15)][k = s*32 + (l>>4)*8 .. +7]
__global__ __launch_bounds__(256) void wprep_kernel(
    const float* __restrict__ W, __bf16* __restrict__ WH, __bf16* __restrict__ WL)
{
    const int tid = blockIdx.x * 256 + threadIdx.x;   // 0..8191
    const int s = tid >> 8;
    const int g = (tid >> 6) & 3;
    const int l = tid & 63;
    const int e  = g * 16 + (l & 15);
    const int k0 = s * 32 + ((l >> 4) & 3) * 8;
    const float* __restrict__ src = W + (size_t)e * D_MODEL + k0;
    bf16x8 h, lo;
#pragma unroll
    for (int i = 0; i < 8; ++i) {
        const float f = src[i];
        const __bf16 hh = (__bf16)f;
        h[i]  = hh;
        lo[i] = (__bf16)(f - (float)hh);
    }
    reinterpret_cast<bf16x8*>(WH)[tid] = h;
    reinterpret_cast<bf16x8*>(WL)[tid] = lo;
}

__global__ __launch_bounds__(BLOCK, 2) void gating_kernel(
    const float* __restrict__ x,
    const __bf16* __restrict__ WH,
    const __bf16* __restrict__ WL,
    const float* __restrict__ b,
    float* __restrict__ out,
    int n_tokens)
{
    __shared__ f32x4 info[4 * TOK_PER_WAVE];   // per-wave {i1,i2,g1,g2} per token

    const int tid = threadIdx.x;
    const int w   = tid >> 6;          // wave in block
    const int l   = tid & 63;          // lane
    const int cl  = l & 15;            // token-in-tile (C/D col)
    const int rg  = (l >> 4) & 3;      // row/k group

    const int wtok0 = blockIdx.x * TOK_PER_BLOCK + w * TOK_PER_WAVE;

    const bf16x8* __restrict__ WHv = reinterpret_cast<const bf16x8*>(WH);
    const bf16x8* __restrict__ WLv = reinterpret_cast<const bf16x8*>(WL);

    // ---- accumulators init with bias: expert e = g*16 + rg*4 + r ----
    f32x4 acc[4][4];                   // [Ttile][Etile]
#pragma unroll
    for (int g = 0; g < 4; ++g) {
        const f32x4 bi = *reinterpret_cast<const f32x4*>(b + g * 16 + rg * 4);
#pragma unroll
        for (int t = 0; t < 4; ++t) acc[t][g] = bi;
    }

    // per-lane x row pointers (frag: tok = Tt*16 + cl, k = s*32 + rg*8 + i)
    const float* xrow[4];
#pragma unroll
    for (int t = 0; t < 4; ++t) {
        int tk = wtok0 + t * 16 + cl;
        tk = tk < n_tokens ? tk : (n_tokens - 1);
        xrow[t] = x + (size_t)tk * D_MODEL + rg * 8;
    }

    f32x4 xa[4][2], xb[4][2];          // double-buffered fp32 x fragments
    bf16x8 wh[4], wl[4];               // single-buffered W fragments

#define LOADX(BUF, S)                                                         \
    _Pragma("unroll")                                                         \
    for (int t = 0; t < 4; ++t) {                                             \
        const float* p = xrow[t] + (S) * 32;                                  \
        BUF[t][0] = *reinterpret_cast<const f32x4*>(p);                       \
        BUF[t][1] = *reinterpret_cast<const f32x4*>(p + 4);                   \
    }
#define LOADW(S)                                                              \
    _Pragma("unroll")                                                         \
    for (int g = 0; g < 4; ++g) {                                             \
        wh[g] = WHv[((S) * 4 + g) * 64 + l];                                  \
        wl[g] = WLv[((S) * 4 + g) * 64 + l];                                  \
    }
#define PROC(XB)                                                              \
    _Pragma("unroll")                                                         \
    for (int t = 0; t < 4; ++t) {                                             \
        bf16x8 bh, bl;                                                        \
        _Pragma("unroll")                                                     \
        for (int i = 0; i < 8; ++i) {                                         \
            const float f = (i < 4) ? XB[t][0][i] : XB[t][1][i - 4];          \
            const __bf16 hh = (__bf16)f;                                      \
            bh[i] = hh;                                                       \
            bl[i] = (__bf16)(f - (float)hh);                                  \
        }                                                                     \
        _Pragma("unroll")                                                     \
        for (int g = 0; g < 4; ++g) {                                         \
            f32x4 c = acc[t][g];                                              \
            c = __builtin_amdgcn_mfma_f32_16x16x32_bf16(wh[g], bh, c, 0, 0, 0); \
            c = __builtin_amdgcn_mfma_f32_16x16x32_bf16(wh[g], bl, c, 0, 0, 0); \
            c = __builtin_amdgcn_mfma_f32_16x16x32_bf16(wl[g], bh, c, 0, 0, 0); \
            acc[t][g] = c;                                                    \
        }                                                                     \
    }

    LOADX(xa, 0);
    for (int s = 0; s < NSTEP; s += 2) {
        LOADW(s);                       // oldest in vmcnt queue
        LOADX(xb, s + 1);               // stays in flight across PROC's W-wait
        PROC(xa);
        LOADW(s + 1);
        if (s + 2 < NSTEP) { LOADX(xa, s + 2); }
        PROC(xb);
    }
#undef LOADX
#undef LOADW
#undef PROC

    // ---- top-2 + softmax per token (token t: lanes cl, cl+16, cl+32, cl+48) ----
    const int wbase = w * TOK_PER_WAVE;
#pragma unroll
    for (int t = 0; t < 4; ++t) {
        float m1 = -INFINITY, m2 = -INFINITY;
        int i1 = 0, i2 = 0;
#pragma unroll
        for (int g = 0; g < 4; ++g) {
#pragma unroll
            for (int r = 0; r < 4; ++r) {
                const float v = acc[t][g][r];
                const int e = g * 16 + rg * 4 + r;
                if (v > m1)      { m2 = m1; i2 = i1; m1 = v; i1 = e; }
                else if (v > m2) { m2 = v;  i2 = e; }
            }
        }
#pragma unroll
        for (int d = 16; d <= 32; d <<= 1) {
            const float om1 = __shfl_xor(m1, d, 64);
            const int   oi1 = __shfl_xor(i1, d, 64);
            const float om2 = __shfl_xor(m2, d, 64);
            const int   oi2 = __shfl_xor(i2, d, 64);
            const bool  sw  = om1 > m1;
            const float a1 = sw ? om1 : m1; const int ai1 = sw ? oi1 : i1;
            const float cc = sw ? m1  : om1; const int ci = sw ? i1  : oi1;
            const float dd = sw ? om2 : m2;  const int di = sw ? oi2 : i2;
            const bool  sw2 = dd > cc;
            m1 = a1; i1 = ai1;
            m2 = sw2 ? dd : cc; i2 = sw2 ? di : ci;
        }
        const float e2 = expf(m2 - m1);
        const float g1 = 1.0f / (1.0f + e2);
        const float g2 = e2 * g1;
        if (rg == 0) {
            f32x4 q;
            q[0] = __int_as_float(i1);
            q[1] = __int_as_float(i2);
            q[2] = g1;
            q[3] = g2;
            info[wbase + t * 16 + cl] = q;   // same-wave DS ordering; no barrier needed
        }
    }

    // ---- coalesced sparse scatter: 64 rows x 16 f32x4 per wave ----
#pragma unroll
    for (int j = 0; j < 16; ++j) {
        const int row = j * 4 + rg;        // 0..63
        const f32x4 q = info[wbase + row];
        const int I1 = __float_as_int(q[0]);
        const int I2 = __float_as_int(q[1]);
        const float G1 = q[2], G2 = q[3];
        const int e0 = cl * 4;
        f32x4 o;
#pragma unroll
        for (int c = 0; c < 4; ++c) {
            const int e = e0 + c;
            o[c] = (e == I1) ? G1 : ((e == I2) ? G2 : 0.0f);
        }
        const int tokg = wtok0 + row;
        if (tokg < n_tokens) {
            reinterpret_cast<f32x4*>(out + (size_t)tokg * N_EXP)[cl] = o;
        }
    }
}

extern "C" void kernel_launch(void* const* d_in, const int* in_sizes, int n_in,
                              void* d_out, int out_size, void* d_ws, size_t ws_size,
                              hipStream_t stream) {
    const float* x = (const float*)d_in[0];
    const float* W = (const float*)d_in[1];
    const float* b = (const float*)d_in[2];
    float* out = (float*)d_out;

    const int n_tokens = in_sizes[0] / D_MODEL;             // 131072

    __bf16* WH = (__bf16*)d_ws;                             // 128 KB
    __bf16* WL = WH + (size_t)N_EXP * D_MODEL;              // 128 KB

    wprep_kernel<<<32, 256, 0, stream>>>(W, WH, WL);

    const int grid = (n_tokens + TOK_PER_BLOCK - 1) / TOK_PER_BLOCK;  // 512
    gating_kernel<<<grid, BLOCK, 0, stream>>>(x, WH, WL, b, out, n_tokens);
}